// Round 2
// baseline (485.250 us; speedup 1.0000x reference)
//
#include <hip/hip_runtime.h>
#include <math.h>

#define LSEQ 2048
#define HDIM 1024
#define BATCH 4
#define ROWS (BATCH * LSEQ)   // 8192
#define NBAND 9               // |i-j| <= 4

// ---------------------------------------------------------------------------
// GEMM (NT): C[m,n] = sum_k A[m,k] * B[n,k] + bias[n]
// A: ROWS x HDIM row-major, B: HDIM x HDIM row-major, C: ROWS x HDIM
// Tile 128x128, BK=8, 256 threads, each thread owns a 2x2 grid of 4x4 blocks.
// LDS stored k-major (transposed) with pad 132 so compute reads are float4
// and conflicts are <=2-way (free on CDNA4).
// ---------------------------------------------------------------------------
__global__ __launch_bounds__(256) void gemm_nt_bias(const float* __restrict__ A,
                                                    const float* __restrict__ B,
                                                    const float* __restrict__ bias,
                                                    float* __restrict__ C) {
    __shared__ float As[8][132];
    __shared__ float Bs[8][132];

    const int tid = threadIdx.x;
    const int row0 = blockIdx.x * 128;   // M tile
    const int col0 = blockIdx.y * 128;   // N tile

    // staging indices: each thread loads one float4 of A and of B per K-step
    const int lr = tid >> 1;            // 0..127 (tile row)
    const int lc = (tid & 1) * 4;       // 0 or 4 (k offset)

    // compute indices
    const int tx = tid & 15;            // n sub-block
    const int ty = tid >> 4;            // m sub-block

    float acc[2][2][4][4];
#pragma unroll
    for (int a = 0; a < 2; a++)
#pragma unroll
        for (int b = 0; b < 2; b++)
#pragma unroll
            for (int c = 0; c < 4; c++)
#pragma unroll
                for (int d = 0; d < 4; d++) acc[a][b][c][d] = 0.f;

    for (int k0 = 0; k0 < HDIM; k0 += 8) {
        float4 av = *reinterpret_cast<const float4*>(&A[(size_t)(row0 + lr) * HDIM + k0 + lc]);
        float4 bv = *reinterpret_cast<const float4*>(&B[(size_t)(col0 + lr) * HDIM + k0 + lc]);
        __syncthreads();   // previous iteration's reads done before overwrite
        As[lc + 0][lr] = av.x; As[lc + 1][lr] = av.y; As[lc + 2][lr] = av.z; As[lc + 3][lr] = av.w;
        Bs[lc + 0][lr] = bv.x; Bs[lc + 1][lr] = bv.y; Bs[lc + 2][lr] = bv.z; Bs[lc + 3][lr] = bv.w;
        __syncthreads();
#pragma unroll
        for (int kk = 0; kk < 8; kk++) {
            float4 a0 = *reinterpret_cast<const float4*>(&As[kk][ty * 4]);
            float4 a1 = *reinterpret_cast<const float4*>(&As[kk][64 + ty * 4]);
            float4 b0 = *reinterpret_cast<const float4*>(&Bs[kk][tx * 4]);
            float4 b1 = *reinterpret_cast<const float4*>(&Bs[kk][64 + tx * 4]);
            float am[2][4] = {{a0.x, a0.y, a0.z, a0.w}, {a1.x, a1.y, a1.z, a1.w}};
            float bw[2][4] = {{b0.x, b0.y, b0.z, b0.w}, {b1.x, b1.y, b1.z, b1.w}};
#pragma unroll
            for (int mi = 0; mi < 2; mi++)
#pragma unroll
                for (int ni = 0; ni < 2; ni++)
#pragma unroll
                    for (int mm = 0; mm < 4; mm++)
#pragma unroll
                        for (int nn = 0; nn < 4; nn++)
                            acc[mi][ni][mm][nn] += am[mi][mm] * bw[ni][nn];
        }
    }

#pragma unroll
    for (int mi = 0; mi < 2; mi++)
#pragma unroll
        for (int mm = 0; mm < 4; mm++) {
            const int r = row0 + mi * 64 + ty * 4 + mm;
#pragma unroll
            for (int ni = 0; ni < 2; ni++) {
                const int c = col0 + ni * 64 + tx * 4;
                float4 o;
                o.x = acc[mi][ni][mm][0] + bias[c + 0];
                o.y = acc[mi][ni][mm][1] + bias[c + 1];
                o.z = acc[mi][ni][mm][2] + bias[c + 2];
                o.w = acc[mi][ni][mm][3] + bias[c + 3];
                *reinterpret_cast<float4*>(&C[(size_t)r * HDIM + c]) = o;
            }
        }
}

// ---------------------------------------------------------------------------
// Band logits + softmax. One wave per (b,i) row: 9 dots of length 1024,
// wave-reduce, softmax over the valid band, write 9 probs to d_ws.
// ---------------------------------------------------------------------------
__global__ __launch_bounds__(256) void band_softmax(const float* __restrict__ qs,
                                                    const float* __restrict__ ks,
                                                    float* __restrict__ band) {
    const int wave = threadIdx.x >> 6;
    const int lane = threadIdx.x & 63;
    const int r = blockIdx.x * 4 + wave;    // 0..8191 (b*L + i)
    const int b = r >> 11;
    const int i = r & (LSEQ - 1);

    const float* qrow = qs + (size_t)r * HDIM;
    const float* kbase = ks + (size_t)b * LSEQ * HDIM;

    float acc[NBAND];
#pragma unroll
    for (int d = 0; d < NBAND; d++) acc[d] = 0.f;

    for (int h = lane; h < HDIM; h += 64) {
        const float qv = qrow[h];
#pragma unroll
        for (int d = 0; d < NBAND; d++) {
            const int j = i + d - 4;
            if (j >= 0 && j < LSEQ)   // wave-uniform branch
                acc[d] += qv * kbase[(size_t)j * HDIM + h];
        }
    }

#pragma unroll
    for (int d = 0; d < NBAND; d++) {
        float v = acc[d];
#pragma unroll
        for (int off = 32; off > 0; off >>= 1) v += __shfl_xor(v, off, 64);
        acc[d] = v;
    }

    if (lane == 0) {
        float m = -1e30f;
#pragma unroll
        for (int d = 0; d < NBAND; d++) {
            const int j = i + d - 4;
            if (j >= 0 && j < LSEQ) m = fmaxf(m, acc[d]);
        }
        float p[NBAND];
        float s = 0.f;
#pragma unroll
        for (int d = 0; d < NBAND; d++) {
            const int j = i + d - 4;
            p[d] = (j >= 0 && j < LSEQ) ? expf(acc[d] - m) : 0.f;
            s += p[d];
        }
        const float inv = 1.f / s;
#pragma unroll
        for (int d = 0; d < NBAND; d++) band[(size_t)r * NBAND + d] = p[d] * inv;
    }
}

// ---------------------------------------------------------------------------
// Expand: dense [B, L, L] output — zeros everywhere, band probs inside band.
// One float4 per thread (rows are 2048 = multiple of 4, so no row crossing).
// ---------------------------------------------------------------------------
__global__ __launch_bounds__(256) void expand_band(const float* __restrict__ band,
                                                   float* __restrict__ out) {
    const size_t idx4 = (size_t)blockIdx.x * 256 + threadIdx.x;
    const size_t flat = idx4 * 4;
    const int j0 = (int)(flat & (LSEQ - 1));
    const size_t row = flat >> 11;           // b*L + i
    const int i = (int)(row & (LSEQ - 1));

    float v[4];
#pragma unroll
    for (int s = 0; s < 4; s++) {
        const int dj = (j0 + s) - i + 4;
        v[s] = (dj >= 0 && dj < NBAND) ? band[row * NBAND + dj] : 0.f;
    }
    float4 o = {v[0], v[1], v[2], v[3]};
    *reinterpret_cast<float4*>(&out[flat]) = o;
}

extern "C" void kernel_launch(void* const* d_in, const int* in_sizes, int n_in,
                              void* d_out, int out_size, void* d_ws, size_t ws_size,
                              hipStream_t stream) {
    const float* q  = (const float*)d_in[0];
    const float* k  = (const float*)d_in[1];
    const float* Wq = (const float*)d_in[2];
    const float* bq = (const float*)d_in[3];
    const float* Wk = (const float*)d_in[4];
    const float* bk = (const float*)d_in[5];
    float* out = (float*)d_out;

    // d_out (16.7M floats) doubles as scratch for qs (8.4M) + ks (8.4M).
    float* qs = out;
    float* ks = out + (size_t)ROWS * HDIM;
    float* band = (float*)d_ws;   // ROWS * 9 floats = 295 KB

    dim3 gemm_grid(ROWS / 128, HDIM / 128);
    gemm_nt_bias<<<gemm_grid, 256, 0, stream>>>(q, Wq, bq, qs);
    gemm_nt_bias<<<gemm_grid, 256, 0, stream>>>(k, Wk, bk, ks);

    band_softmax<<<ROWS / 4, 256, 0, stream>>>(qs, ks, band);

    expand_band<<<(size_t)ROWS * LSEQ / 4 / 256, 256, 0, stream>>>(band, out);
}

// Round 3
// 193.738 us; speedup vs baseline: 2.5047x; 2.5047x over previous
//
#include <hip/hip_runtime.h>
#include <math.h>

#define LSEQ 2048
#define HDIM 1024
#define BATCH 4
#define ROWS (BATCH * LSEQ)   // 8192
#define NBAND 9               // |i-j| <= 4

typedef __attribute__((ext_vector_type(8))) short bf16x8;
typedef __attribute__((ext_vector_type(4))) float f32x4;

#define AS3 __attribute__((address_space(3)))
#define AS1 __attribute__((address_space(1)))

__device__ __forceinline__ void gload16(const void* gp, void* lp) {
    __builtin_amdgcn_global_load_lds((AS1 const unsigned*)gp, (AS3 unsigned*)lp, 16, 0, 0);
}

// round-to-nearest-even fp32 -> bf16 (as u16)
__device__ __forceinline__ unsigned short f2bf(float x) {
    unsigned u = __float_as_uint(x);
    u += 0x7FFFu + ((u >> 16) & 1u);
    return (unsigned short)(u >> 16);
}
__device__ __forceinline__ float bf2f(unsigned short h) {
    return __uint_as_float(((unsigned)h) << 16);
}

// ---------------------------------------------------------------------------
// Split fp32 -> (hi, lo) bf16 pair. x = hi + lo to ~2^-17 relative.
// ---------------------------------------------------------------------------
__global__ __launch_bounds__(256) void convert_split(const float* __restrict__ src,
                                                     unsigned short* __restrict__ hi,
                                                     unsigned short* __restrict__ lo,
                                                     int n4) {
    const int idx = blockIdx.x * 256 + threadIdx.x;
    if (idx >= n4) return;
    float4 v = reinterpret_cast<const float4*>(src)[idx];
    ushort4 h, l;
    h.x = f2bf(v.x); l.x = f2bf(v.x - bf2f(h.x));
    h.y = f2bf(v.y); l.y = f2bf(v.y - bf2f(h.y));
    h.z = f2bf(v.z); l.z = f2bf(v.z - bf2f(h.z));
    h.w = f2bf(v.w); l.w = f2bf(v.w - bf2f(h.w));
    reinterpret_cast<ushort4*>(hi)[idx] = h;
    reinterpret_cast<ushort4*>(lo)[idx] = l;
}

// ---------------------------------------------------------------------------
// Split-bf16 MFMA GEMM (NT): C[m,n] = sum_k A[m,k]*B[n,k] + bias[n]
// A: ROWS x 1024 (hi/lo bf16), B: 1024 x 1024 (hi/lo bf16), C fp32.
// 128x128 tile, BK=32, 256 threads = 4 waves (2x2), each wave 64x64 out.
// global_load_lds width-16 staging, LDS linear dest + pre-swizzled global
// source; read side applies the same involution cb ^= (row>>1)&3.
// 3 MFMA per fragment pair: hi*hi + hi*lo + lo*hi (fp32 accumulate).
// ---------------------------------------------------------------------------
__global__ __launch_bounds__(256, 2) void gemm_mfma_split(
        const unsigned short* __restrict__ Ahi, const unsigned short* __restrict__ Alo,
        const unsigned short* __restrict__ Bhi, const unsigned short* __restrict__ Blo,
        const float* __restrict__ bias, float* __restrict__ C) {
    // 4 tiles of 128x32 bf16 (8 KB each): Ahi, Alo, Bhi, Blo
    __shared__ unsigned short sh[4 * 4096];
    const int AHI = 0, ALO = 4096, BHI = 8192, BLO = 12288;

    const int tid = threadIdx.x;
    const int w = tid >> 6;           // wave 0..3
    const int l = tid & 63;           // lane
    const int wr = w >> 1;            // wave row (0..1)
    const int wc = w & 1;             // wave col (0..1)
    const int row0 = blockIdx.x * 128;
    const int col0 = blockIdx.y * 128;

    // staging geometry: per tile, 8 segs of 1024B; wave w does segs w and w+4.
    // LDS linear: seg*1024 + lane*16 bytes -> row = seg*16 + l/4, cb' = l&3.
    // Global source pre-swizzled: cb = cb' ^ ((row>>1)&3).
    const int srow0 = (l >> 2);            // + seg*16
    const int scbp = l & 3;

    f32x4 acc[4][4];
#pragma unroll
    for (int m = 0; m < 4; m++)
#pragma unroll
        for (int n = 0; n < 4; n++) acc[m][n] = (f32x4){0.f, 0.f, 0.f, 0.f};

    // fragment read addresses (tile-local), swizzled
    const int fr_a[4] = {wr * 64 + 0 * 16 + (l & 15), wr * 64 + 1 * 16 + (l & 15),
                         wr * 64 + 2 * 16 + (l & 15), wr * 64 + 3 * 16 + (l & 15)};
    const int fr_b[4] = {wc * 64 + 0 * 16 + (l & 15), wc * 64 + 1 * 16 + (l & 15),
                         wc * 64 + 2 * 16 + (l & 15), wc * 64 + 3 * 16 + (l & 15)};
    const int cb = l >> 4;            // 0..3 (k block of 8 bf16)

    for (int k0 = 0; k0 < HDIM; k0 += 32) {
        // ---- stage 4 tiles (8 global_load_lds per thread) ----
#pragma unroll
        for (int i = 0; i < 2; i++) {
            const int seg = i * 4 + w;
            const int row = seg * 16 + srow0;               // 0..127
            const int cbs = scbp ^ ((row >> 1) & 3);        // global col-block
            const unsigned short* ga = Ahi + (size_t)(row0 + row) * HDIM + k0 + cbs * 8;
            const unsigned short* gal = Alo + (size_t)(row0 + row) * HDIM + k0 + cbs * 8;
            const unsigned short* gb = Bhi + (size_t)(col0 + row) * HDIM + k0 + cbs * 8;
            const unsigned short* gbl = Blo + (size_t)(col0 + row) * HDIM + k0 + cbs * 8;
            gload16(ga,  &sh[AHI + seg * 512]);
            gload16(gal, &sh[ALO + seg * 512]);
            gload16(gb,  &sh[BHI + seg * 512]);
            gload16(gbl, &sh[BLO + seg * 512]);
        }
        __syncthreads();   // drains vmcnt before barrier (compiler-inserted)

        // ---- read fragments ----
        bf16x8 ah[4], al[4], bh[4], bl[4];
#pragma unroll
        for (int m = 0; m < 4; m++) {
            const int r = fr_a[m];
            const int cbs = cb ^ ((r >> 1) & 3);
            ah[m] = *reinterpret_cast<const bf16x8*>(&sh[AHI + r * 32 + cbs * 8]);
            al[m] = *reinterpret_cast<const bf16x8*>(&sh[ALO + r * 32 + cbs * 8]);
        }
#pragma unroll
        for (int n = 0; n < 4; n++) {
            const int r = fr_b[n];
            const int cbs = cb ^ ((r >> 1) & 3);
            bh[n] = *reinterpret_cast<const bf16x8*>(&sh[BHI + r * 32 + cbs * 8]);
            bl[n] = *reinterpret_cast<const bf16x8*>(&sh[BLO + r * 32 + cbs * 8]);
        }

        // ---- 48 MFMA: hi*hi + hi*lo + lo*hi ----
#pragma unroll
        for (int m = 0; m < 4; m++)
#pragma unroll
            for (int n = 0; n < 4; n++) {
                acc[m][n] = __builtin_amdgcn_mfma_f32_16x16x32_bf16(ah[m], bh[n], acc[m][n], 0, 0, 0);
                acc[m][n] = __builtin_amdgcn_mfma_f32_16x16x32_bf16(ah[m], bl[n], acc[m][n], 0, 0, 0);
                acc[m][n] = __builtin_amdgcn_mfma_f32_16x16x32_bf16(al[m], bh[n], acc[m][n], 0, 0, 0);
            }
        __syncthreads();   // reads done before next iteration overwrites
    }

    // ---- epilogue: C/D layout col=lane&15, row=(lane>>4)*4+reg ----
    const int lcol = l & 15;
    const int lrow = (l >> 4) * 4;
#pragma unroll
    for (int n = 0; n < 4; n++) {
        const int colg = col0 + wc * 64 + n * 16 + lcol;
        const float bv = bias[colg];
#pragma unroll
        for (int m = 0; m < 4; m++) {
            const int rowg = row0 + wr * 64 + m * 16 + lrow;
#pragma unroll
            for (int v = 0; v < 4; v++)
                C[(size_t)(rowg + v) * HDIM + colg] = acc[m][n][v] + bv;
        }
    }
}

// ---------------------------------------------------------------------------
// Fallback fp32 GEMM (NT) — used only if ws_size too small for bf16 buffers.
// ---------------------------------------------------------------------------
__global__ __launch_bounds__(256) void gemm_nt_bias(const float* __restrict__ A,
                                                    const float* __restrict__ B,
                                                    const float* __restrict__ bias,
                                                    float* __restrict__ C) {
    __shared__ float As[8][132];
    __shared__ float Bs[8][132];
    const int tid = threadIdx.x;
    const int row0 = blockIdx.x * 128;
    const int col0 = blockIdx.y * 128;
    const int lr = tid >> 1;
    const int lc = (tid & 1) * 4;
    const int tx = tid & 15;
    const int ty = tid >> 4;
    float acc[2][2][4][4];
#pragma unroll
    for (int a = 0; a < 2; a++)
#pragma unroll
        for (int b = 0; b < 2; b++)
#pragma unroll
            for (int c = 0; c < 4; c++)
#pragma unroll
                for (int d = 0; d < 4; d++) acc[a][b][c][d] = 0.f;
    for (int k0 = 0; k0 < HDIM; k0 += 8) {
        float4 av = *reinterpret_cast<const float4*>(&A[(size_t)(row0 + lr) * HDIM + k0 + lc]);
        float4 bv = *reinterpret_cast<const float4*>(&B[(size_t)(col0 + lr) * HDIM + k0 + lc]);
        __syncthreads();
        As[lc + 0][lr] = av.x; As[lc + 1][lr] = av.y; As[lc + 2][lr] = av.z; As[lc + 3][lr] = av.w;
        Bs[lc + 0][lr] = bv.x; Bs[lc + 1][lr] = bv.y; Bs[lc + 2][lr] = bv.z; Bs[lc + 3][lr] = bv.w;
        __syncthreads();
#pragma unroll
        for (int kk = 0; kk < 8; kk++) {
            float4 a0 = *reinterpret_cast<const float4*>(&As[kk][ty * 4]);
            float4 a1 = *reinterpret_cast<const float4*>(&As[kk][64 + ty * 4]);
            float4 b0 = *reinterpret_cast<const float4*>(&Bs[kk][tx * 4]);
            float4 b1 = *reinterpret_cast<const float4*>(&Bs[kk][64 + tx * 4]);
            float am[2][4] = {{a0.x, a0.y, a0.z, a0.w}, {a1.x, a1.y, a1.z, a1.w}};
            float bw[2][4] = {{b0.x, b0.y, b0.z, b0.w}, {b1.x, b1.y, b1.z, b1.w}};
#pragma unroll
            for (int mi = 0; mi < 2; mi++)
#pragma unroll
                for (int ni = 0; ni < 2; ni++)
#pragma unroll
                    for (int mm = 0; mm < 4; mm++)
#pragma unroll
                        for (int nn = 0; nn < 4; nn++)
                            acc[mi][ni][mm][nn] += am[mi][mm] * bw[ni][nn];
        }
    }
#pragma unroll
    for (int mi = 0; mi < 2; mi++)
#pragma unroll
        for (int mm = 0; mm < 4; mm++) {
            const int r = row0 + mi * 64 + ty * 4 + mm;
#pragma unroll
            for (int ni = 0; ni < 2; ni++) {
                const int c = col0 + ni * 64 + tx * 4;
                float4 o;
                o.x = acc[mi][ni][mm][0] + bias[c + 0];
                o.y = acc[mi][ni][mm][1] + bias[c + 1];
                o.z = acc[mi][ni][mm][2] + bias[c + 2];
                o.w = acc[mi][ni][mm][3] + bias[c + 3];
                *reinterpret_cast<float4*>(&C[(size_t)r * HDIM + c]) = o;
            }
        }
}

// ---------------------------------------------------------------------------
// Band logits + softmax (unchanged).
// ---------------------------------------------------------------------------
__global__ __launch_bounds__(256) void band_softmax(const float* __restrict__ qs,
                                                    const float* __restrict__ ks,
                                                    float* __restrict__ band) {
    const int wave = threadIdx.x >> 6;
    const int lane = threadIdx.x & 63;
    const int r = blockIdx.x * 4 + wave;
    const int b = r >> 11;
    const int i = r & (LSEQ - 1);
    const float* qrow = qs + (size_t)r * HDIM;
    const float* kbase = ks + (size_t)b * LSEQ * HDIM;
    float acc[NBAND];
#pragma unroll
    for (int d = 0; d < NBAND; d++) acc[d] = 0.f;
    for (int h = lane; h < HDIM; h += 64) {
        const float qv = qrow[h];
#pragma unroll
        for (int d = 0; d < NBAND; d++) {
            const int j = i + d - 4;
            if (j >= 0 && j < LSEQ)
                acc[d] += qv * kbase[(size_t)j * HDIM + h];
        }
    }
#pragma unroll
    for (int d = 0; d < NBAND; d++) {
        float v = acc[d];
#pragma unroll
        for (int off = 32; off > 0; off >>= 1) v += __shfl_xor(v, off, 64);
        acc[d] = v;
    }
    if (lane == 0) {
        float m = -1e30f;
#pragma unroll
        for (int d = 0; d < NBAND; d++) {
            const int j = i + d - 4;
            if (j >= 0 && j < LSEQ) m = fmaxf(m, acc[d]);
        }
        float p[NBAND];
        float s = 0.f;
#pragma unroll
        for (int d = 0; d < NBAND; d++) {
            const int j = i + d - 4;
            p[d] = (j >= 0 && j < LSEQ) ? expf(acc[d] - m) : 0.f;
            s += p[d];
        }
        const float inv = 1.f / s;
#pragma unroll
        for (int d = 0; d < NBAND; d++) band[(size_t)r * NBAND + d] = p[d] * inv;
    }
}

// ---------------------------------------------------------------------------
// Expand band probs into dense [B, L, L] output (unchanged).
// ---------------------------------------------------------------------------
__global__ __launch_bounds__(256) void expand_band(const float* __restrict__ band,
                                                   float* __restrict__ out) {
    const size_t idx4 = (size_t)blockIdx.x * 256 + threadIdx.x;
    const size_t flat = idx4 * 4;
    const int j0 = (int)(flat & (LSEQ - 1));
    const size_t row = flat >> 11;
    const int i = (int)(row & (LSEQ - 1));
    float v[4];
#pragma unroll
    for (int s = 0; s < 4; s++) {
        const int dj = (j0 + s) - i + 4;
        v[s] = (dj >= 0 && dj < NBAND) ? band[row * NBAND + dj] : 0.f;
    }
    float4 o = {v[0], v[1], v[2], v[3]};
    *reinterpret_cast<float4*>(&out[flat]) = o;
}

extern "C" void kernel_launch(void* const* d_in, const int* in_sizes, int n_in,
                              void* d_out, int out_size, void* d_ws, size_t ws_size,
                              hipStream_t stream) {
    const float* q  = (const float*)d_in[0];
    const float* k  = (const float*)d_in[1];
    const float* Wq = (const float*)d_in[2];
    const float* bq = (const float*)d_in[3];
    const float* Wk = (const float*)d_in[4];
    const float* bk = (const float*)d_in[5];
    float* out = (float*)d_out;

    float* qs = out;                              // [8192,1024] fp32
    float* ks = out + (size_t)ROWS * HDIM;        // [8192,1024] fp32
    float* band = (float*)d_ws;                   // ROWS*9 fp32 = 295 KB

    const size_t bandB = (size_t)ROWS * NBAND * sizeof(float);
    const size_t xB = (size_t)ROWS * HDIM * sizeof(unsigned short);   // 16 MB
    const size_t wB = (size_t)HDIM * HDIM * sizeof(unsigned short);   // 2 MB
    const size_t need = bandB + 2 * xB + 2 * wB;  // ~38 MB

    dim3 gemm_grid(ROWS / 128, HDIM / 128);

    if (ws_size >= need) {
        unsigned short* Xhi = (unsigned short*)((char*)d_ws + bandB);
        unsigned short* Xlo = Xhi + (size_t)ROWS * HDIM;
        unsigned short* Whi = Xlo + (size_t)ROWS * HDIM;
        unsigned short* Wlo = Whi + (size_t)HDIM * HDIM;

        const int n4x = ROWS * HDIM / 4;   // 2,097,152
        const int n4w = HDIM * HDIM / 4;   // 262,144

        // qs = q @ Wq^T + bq
        convert_split<<<n4w / 256, 256, 0, stream>>>(Wq, Whi, Wlo, n4w);
        convert_split<<<n4x / 256, 256, 0, stream>>>(q, Xhi, Xlo, n4x);
        gemm_mfma_split<<<gemm_grid, 256, 0, stream>>>(Xhi, Xlo, Whi, Wlo, bq, qs);
        // ks = k @ Wk^T + bk (reuse the same scratch)
        convert_split<<<n4w / 256, 256, 0, stream>>>(Wk, Whi, Wlo, n4w);
        convert_split<<<n4x / 256, 256, 0, stream>>>(k, Xhi, Xlo, n4x);
        gemm_mfma_split<<<gemm_grid, 256, 0, stream>>>(Xhi, Xlo, Whi, Wlo, bk, ks);
    } else {
        gemm_nt_bias<<<gemm_grid, 256, 0, stream>>>(q, Wq, bq, qs);
        gemm_nt_bias<<<gemm_grid, 256, 0, stream>>>(k, Wk, bk, ks);
    }

    band_softmax<<<ROWS / 4, 256, 0, stream>>>(qs, ks, band);

    expand_band<<<(size_t)ROWS * LSEQ / 4 / 256, 256, 0, stream>>>(band, out);
}

// Round 4
// 159.053 us; speedup vs baseline: 3.0509x; 1.2181x over previous
//
#include <hip/hip_runtime.h>
#include <math.h>

#define LSEQ 2048
#define HDIM 1024
#define BATCH 4
#define ROWS (BATCH * LSEQ)   // 8192
#define NBAND 9               // |i-j| <= 4

typedef __attribute__((ext_vector_type(8))) short bf16x8;
typedef __attribute__((ext_vector_type(4))) float f32x4;
typedef __attribute__((ext_vector_type(8))) unsigned short u16x8;

#define AS3 __attribute__((address_space(3)))
#define AS1 __attribute__((address_space(1)))

__device__ __forceinline__ void gload16(const void* gp, void* lp) {
    __builtin_amdgcn_global_load_lds((AS1 const unsigned*)gp, (AS3 unsigned*)lp, 16, 0, 0);
}

__device__ __forceinline__ unsigned short f2bf(float x) {
    unsigned u = __float_as_uint(x);
    u += 0x7FFFu + ((u >> 16) & 1u);
    return (unsigned short)(u >> 16);
}
__device__ __forceinline__ float bf2f(unsigned short h) {
    return __uint_as_float(((unsigned)h) << 16);
}

// ---------------------------------------------------------------------------
// w partial: wpart[blk][c] = sum_{h in blk range} Wk[h,c] * bq[h]
// ---------------------------------------------------------------------------
__global__ __launch_bounds__(256) void wpart_kernel(const float* __restrict__ Wk,
                                                    const float* __restrict__ bq,
                                                    float* __restrict__ wpart) {
    const int b = blockIdx.x;          // 0..15, h range [b*64, b*64+64)
    const int c0 = threadIdx.x * 4;
    float4 acc = {0.f, 0.f, 0.f, 0.f};
    for (int hh = 0; hh < 64; hh++) {
        const int h = b * 64 + hh;
        const float s = bq[h];
        float4 v = *reinterpret_cast<const float4*>(&Wk[(size_t)h * HDIM + c0]);
        acc.x += v.x * s; acc.y += v.y * s; acc.z += v.z * s; acc.w += v.w * s;
    }
    *reinterpret_cast<float4*>(&wpart[(size_t)b * HDIM + c0]) = acc;
}

// blocks 0..3: w[c] = sum_b wpart[b][c];  blocks 4..7: zerobias = 0
__global__ __launch_bounds__(256) void wreduce_zero(const float* __restrict__ wpart,
                                                    float* __restrict__ w,
                                                    float* __restrict__ zerobias) {
    const int blk = blockIdx.x;
    const int t = threadIdx.x;
    if (blk < 4) {
        const int c = blk * 256 + t;
        float s = 0.f;
#pragma unroll
        for (int b = 0; b < 16; b++) s += wpart[(size_t)b * HDIM + c];
        w[c] = s;
    } else {
        zerobias[(blk - 4) * 256 + t] = 0.f;
    }
}

// ---------------------------------------------------------------------------
// Transposed split-convert: dst[n,h] = split(src[h,n]); z=0 -> Wq, z=1 -> Wk
// 64x64 tiles via LDS.
// ---------------------------------------------------------------------------
__global__ __launch_bounds__(256) void transpose_convert(const float* __restrict__ Wq,
                                                         const float* __restrict__ Wk,
                                                         unsigned short* __restrict__ qhi,
                                                         unsigned short* __restrict__ qlo,
                                                         unsigned short* __restrict__ khi,
                                                         unsigned short* __restrict__ klo) {
    __shared__ float tile[64][65];
    const int z = blockIdx.z;
    const float* src = z ? Wk : Wq;
    unsigned short* dh = z ? khi : qhi;
    unsigned short* dl = z ? klo : qlo;
    const int n0 = blockIdx.x * 64;
    const int h0 = blockIdx.y * 64;
    const int tid = threadIdx.x;

#pragma unroll
    for (int p = 0; p < 4; p++) {
        const int h = p * 16 + (tid >> 4);
        const int n = (tid & 15) * 4;
        float4 v = *reinterpret_cast<const float4*>(&src[(size_t)(h0 + h) * HDIM + n0 + n]);
        tile[h][n + 0] = v.x; tile[h][n + 1] = v.y; tile[h][n + 2] = v.z; tile[h][n + 3] = v.w;
    }
    __syncthreads();
#pragma unroll
    for (int p = 0; p < 2; p++) {
        const int n = p * 32 + (tid >> 3);
        const int h = (tid & 7) * 8;
        u16x8 hv, lv;
#pragma unroll
        for (int j = 0; j < 8; j++) {
            float x = tile[h + j][n];
            unsigned short hb = f2bf(x);
            hv[j] = hb;
            lv[j] = f2bf(x - bf2f(hb));
        }
        *reinterpret_cast<u16x8*>(&dh[(size_t)(n0 + n) * HDIM + h0 + h]) = hv;
        *reinterpret_cast<u16x8*>(&dl[(size_t)(n0 + n) * HDIM + h0 + h]) = lv;
    }
}

// ---------------------------------------------------------------------------
// Fused: split-convert k rows to bf16 hi/lo AND beta[r] = k_r . w
// One block (256 thr) per row.
// ---------------------------------------------------------------------------
__global__ __launch_bounds__(256) void convert_k_beta(const float* __restrict__ k,
                                                      const float* __restrict__ w,
                                                      unsigned short* __restrict__ Xhi,
                                                      unsigned short* __restrict__ Xlo,
                                                      float* __restrict__ beta) {
    __shared__ float red[4];
    const int r = blockIdx.x;
    const int t = threadIdx.x;
    float4 v = *reinterpret_cast<const float4*>(&k[(size_t)r * HDIM + t * 4]);
    float4 wv = *reinterpret_cast<const float4*>(&w[t * 4]);
    ushort4 h, l;
    h.x = f2bf(v.x); l.x = f2bf(v.x - bf2f(h.x));
    h.y = f2bf(v.y); l.y = f2bf(v.y - bf2f(h.y));
    h.z = f2bf(v.z); l.z = f2bf(v.z - bf2f(h.z));
    h.w = f2bf(v.w); l.w = f2bf(v.w - bf2f(h.w));
    reinterpret_cast<ushort4*>(Xhi)[(size_t)r * 256 + t] = h;
    reinterpret_cast<ushort4*>(Xlo)[(size_t)r * 256 + t] = l;
    float d = v.x * wv.x + v.y * wv.y + v.z * wv.z + v.w * wv.w;
#pragma unroll
    for (int off = 32; off > 0; off >>= 1) d += __shfl_xor(d, off, 64);
    if ((t & 63) == 0) red[t >> 6] = d;
    __syncthreads();
    if (t == 0) beta[r] = red[0] + red[1] + red[2] + red[3];
}

// ---------------------------------------------------------------------------
// Split-bf16 MFMA GEMM (NT) + bias: C[m,n] = sum_k A[m,k]*B[n,k] + bias[n]
// (verified round 3) 128x128 tile, BK=32, 4 waves.
// ---------------------------------------------------------------------------
__global__ __launch_bounds__(256, 2) void gemm_mfma_split(
        const unsigned short* __restrict__ Ahi, const unsigned short* __restrict__ Alo,
        const unsigned short* __restrict__ Bhi, const unsigned short* __restrict__ Blo,
        const float* __restrict__ bias, float* __restrict__ C) {
    __shared__ unsigned short sh[4 * 4096];
    const int AHI = 0, ALO = 4096, BHI = 8192, BLO = 12288;
    const int tid = threadIdx.x;
    const int w = tid >> 6, l = tid & 63;
    const int wr = w >> 1, wc = w & 1;
    const int row0 = blockIdx.x * 128, col0 = blockIdx.y * 128;
    const int srow0 = (l >> 2), scbp = l & 3;

    f32x4 acc[4][4];
#pragma unroll
    for (int m = 0; m < 4; m++)
#pragma unroll
        for (int n = 0; n < 4; n++) acc[m][n] = (f32x4){0.f, 0.f, 0.f, 0.f};

    const int fr_a[4] = {wr * 64 + (l & 15), wr * 64 + 16 + (l & 15),
                         wr * 64 + 32 + (l & 15), wr * 64 + 48 + (l & 15)};
    const int fr_b[4] = {wc * 64 + (l & 15), wc * 64 + 16 + (l & 15),
                         wc * 64 + 32 + (l & 15), wc * 64 + 48 + (l & 15)};
    const int cb = l >> 4;

    for (int k0 = 0; k0 < HDIM; k0 += 32) {
#pragma unroll
        for (int i = 0; i < 2; i++) {
            const int seg = i * 4 + w;
            const int row = seg * 16 + srow0;
            const int cbs = scbp ^ ((row >> 1) & 3);
            gload16(Ahi + (size_t)(row0 + row) * HDIM + k0 + cbs * 8, &sh[AHI + seg * 512]);
            gload16(Alo + (size_t)(row0 + row) * HDIM + k0 + cbs * 8, &sh[ALO + seg * 512]);
            gload16(Bhi + (size_t)(col0 + row) * HDIM + k0 + cbs * 8, &sh[BHI + seg * 512]);
            gload16(Blo + (size_t)(col0 + row) * HDIM + k0 + cbs * 8, &sh[BLO + seg * 512]);
        }
        __syncthreads();

        bf16x8 ah[4], al[4], bh[4], bl[4];
#pragma unroll
        for (int m = 0; m < 4; m++) {
            const int r = fr_a[m];
            const int cbs = cb ^ ((r >> 1) & 3);
            ah[m] = *reinterpret_cast<const bf16x8*>(&sh[AHI + r * 32 + cbs * 8]);
            al[m] = *reinterpret_cast<const bf16x8*>(&sh[ALO + r * 32 + cbs * 8]);
        }
#pragma unroll
        for (int n = 0; n < 4; n++) {
            const int r = fr_b[n];
            const int cbs = cb ^ ((r >> 1) & 3);
            bh[n] = *reinterpret_cast<const bf16x8*>(&sh[BHI + r * 32 + cbs * 8]);
            bl[n] = *reinterpret_cast<const bf16x8*>(&sh[BLO + r * 32 + cbs * 8]);
        }
#pragma unroll
        for (int m = 0; m < 4; m++)
#pragma unroll
            for (int n = 0; n < 4; n++) {
                acc[m][n] = __builtin_amdgcn_mfma_f32_16x16x32_bf16(ah[m], bh[n], acc[m][n], 0, 0, 0);
                acc[m][n] = __builtin_amdgcn_mfma_f32_16x16x32_bf16(ah[m], bl[n], acc[m][n], 0, 0, 0);
                acc[m][n] = __builtin_amdgcn_mfma_f32_16x16x32_bf16(al[m], bh[n], acc[m][n], 0, 0, 0);
            }
        __syncthreads();
    }

    const int lcol = l & 15, lrow = (l >> 4) * 4;
#pragma unroll
    for (int n = 0; n < 4; n++) {
        const int colg = col0 + wc * 64 + n * 16 + lcol;
        const float bv = bias[colg];
#pragma unroll
        for (int m = 0; m < 4; m++) {
            const int rowg = row0 + wr * 64 + m * 16 + lrow;
#pragma unroll
            for (int v = 0; v < 4; v++)
                C[(size_t)(rowg + v) * HDIM + colg] = acc[m][n][v] + bv;
        }
    }
}

// ---------------------------------------------------------------------------
// Same GEMM core, split-K variant for M = WqT @ WkT^T: grid (8,8,8);
// z-slice computes K range [z*128, z*128+128) into Cparts + z*1M floats.
// ---------------------------------------------------------------------------
__global__ __launch_bounds__(256, 2) void gemm_part(
        const unsigned short* __restrict__ Ahi, const unsigned short* __restrict__ Alo,
        const unsigned short* __restrict__ Bhi, const unsigned short* __restrict__ Blo,
        float* __restrict__ Cparts) {
    __shared__ unsigned short sh[4 * 4096];
    const int AHI = 0, ALO = 4096, BHI = 8192, BLO = 12288;
    const int tid = threadIdx.x;
    const int w = tid >> 6, l = tid & 63;
    const int wr = w >> 1, wc = w & 1;
    const int row0 = blockIdx.x * 128, col0 = blockIdx.y * 128;
    const int kbeg = blockIdx.z * 128;
    float* C = Cparts + (size_t)blockIdx.z * HDIM * HDIM;
    const int srow0 = (l >> 2), scbp = l & 3;

    f32x4 acc[4][4];
#pragma unroll
    for (int m = 0; m < 4; m++)
#pragma unroll
        for (int n = 0; n < 4; n++) acc[m][n] = (f32x4){0.f, 0.f, 0.f, 0.f};

    const int fr_a[4] = {wr * 64 + (l & 15), wr * 64 + 16 + (l & 15),
                         wr * 64 + 32 + (l & 15), wr * 64 + 48 + (l & 15)};
    const int fr_b[4] = {wc * 64 + (l & 15), wc * 64 + 16 + (l & 15),
                         wc * 64 + 32 + (l & 15), wc * 64 + 48 + (l & 15)};
    const int cb = l >> 4;

    for (int k0 = kbeg; k0 < kbeg + 128; k0 += 32) {
#pragma unroll
        for (int i = 0; i < 2; i++) {
            const int seg = i * 4 + w;
            const int row = seg * 16 + srow0;
            const int cbs = scbp ^ ((row >> 1) & 3);
            gload16(Ahi + (size_t)(row0 + row) * HDIM + k0 + cbs * 8, &sh[AHI + seg * 512]);
            gload16(Alo + (size_t)(row0 + row) * HDIM + k0 + cbs * 8, &sh[ALO + seg * 512]);
            gload16(Bhi + (size_t)(col0 + row) * HDIM + k0 + cbs * 8, &sh[BHI + seg * 512]);
            gload16(Blo + (size_t)(col0 + row) * HDIM + k0 + cbs * 8, &sh[BLO + seg * 512]);
        }
        __syncthreads();

        bf16x8 ah[4], al[4], bh[4], bl[4];
#pragma unroll
        for (int m = 0; m < 4; m++) {
            const int r = fr_a[m];
            const int cbs = cb ^ ((r >> 1) & 3);
            ah[m] = *reinterpret_cast<const bf16x8*>(&sh[AHI + r * 32 + cbs * 8]);
            al[m] = *reinterpret_cast<const bf16x8*>(&sh[ALO + r * 32 + cbs * 8]);
        }
#pragma unroll
        for (int n = 0; n < 4; n++) {
            const int r = fr_b[n];
            const int cbs = cb ^ ((r >> 1) & 3);
            bh[n] = *reinterpret_cast<const bf16x8*>(&sh[BHI + r * 32 + cbs * 8]);
            bl[n] = *reinterpret_cast<const bf16x8*>(&sh[BLO + r * 32 + cbs * 8]);
        }
#pragma unroll
        for (int m = 0; m < 4; m++)
#pragma unroll
            for (int n = 0; n < 4; n++) {
                acc[m][n] = __builtin_amdgcn_mfma_f32_16x16x32_bf16(ah[m], bh[n], acc[m][n], 0, 0, 0);
                acc[m][n] = __builtin_amdgcn_mfma_f32_16x16x32_bf16(ah[m], bl[n], acc[m][n], 0, 0, 0);
                acc[m][n] = __builtin_amdgcn_mfma_f32_16x16x32_bf16(al[m], bh[n], acc[m][n], 0, 0, 0);
            }
        __syncthreads();
    }

    const int lcol = l & 15, lrow = (l >> 4) * 4;
#pragma unroll
    for (int n = 0; n < 4; n++) {
        const int colg = col0 + wc * 64 + n * 16 + lcol;
#pragma unroll
        for (int m = 0; m < 4; m++) {
            const int rowg = row0 + wr * 64 + m * 16 + lrow;
#pragma unroll
            for (int v = 0; v < 4; v++)
                C[(size_t)(rowg + v) * HDIM + colg] = acc[m][n][v];
        }
    }
}

// ---------------------------------------------------------------------------
// Reduce 8 M-parts and split-convert to bf16 hi/lo.
// ---------------------------------------------------------------------------
__global__ __launch_bounds__(256) void reduceM_convert(const float* __restrict__ Mparts,
                                                       unsigned short* __restrict__ Mhi,
                                                       unsigned short* __restrict__ Mlo) {
    const int idx4 = blockIdx.x * 256 + threadIdx.x;   // 0 .. 1M/4
    float4 s = {0.f, 0.f, 0.f, 0.f};
#pragma unroll
    for (int z = 0; z < 8; z++) {
        float4 v = reinterpret_cast<const float4*>(Mparts + (size_t)z * HDIM * HDIM)[idx4];
        s.x += v.x; s.y += v.y; s.z += v.z; s.w += v.w;
    }
    ushort4 h, l;
    h.x = f2bf(s.x); l.x = f2bf(s.x - bf2f(h.x));
    h.y = f2bf(s.y); l.y = f2bf(s.y - bf2f(h.y));
    h.z = f2bf(s.z); l.z = f2bf(s.z - bf2f(h.z));
    h.w = f2bf(s.w); l.w = f2bf(s.w - bf2f(h.w));
    reinterpret_cast<ushort4*>(Mhi)[idx4] = h;
    reinterpret_cast<ushort4*>(Mlo)[idx4] = l;
}

// ---------------------------------------------------------------------------
// Band logits + softmax: logit_d = q_i . t_j + beta_j  (row consts dropped).
// One wave per row.
// ---------------------------------------------------------------------------
__global__ __launch_bounds__(256) void band_softmax_v2(const float* __restrict__ q,
                                                       const float* __restrict__ t,
                                                       const float* __restrict__ beta,
                                                       float* __restrict__ band) {
    const int wave = threadIdx.x >> 6;
    const int lane = threadIdx.x & 63;
    const int r = blockIdx.x * 4 + wave;
    const int b = r >> 11;
    const int i = r & (LSEQ - 1);
    const float* qrow = q + (size_t)r * HDIM;
    const float* tbase = t + (size_t)b * LSEQ * HDIM;

    float acc[NBAND];
#pragma unroll
    for (int d = 0; d < NBAND; d++) acc[d] = 0.f;
    for (int h = lane; h < HDIM; h += 64) {
        const float qv = qrow[h];
#pragma unroll
        for (int d = 0; d < NBAND; d++) {
            const int j = i + d - 4;
            if (j >= 0 && j < LSEQ)
                acc[d] += qv * tbase[(size_t)j * HDIM + h];
        }
    }
#pragma unroll
    for (int d = 0; d < NBAND; d++) {
        float v = acc[d];
#pragma unroll
        for (int off = 32; off > 0; off >>= 1) v += __shfl_xor(v, off, 64);
        acc[d] = v;
    }
    if (lane == 0) {
        const float* brow = beta + (size_t)b * LSEQ;
        float m = -1e30f;
#pragma unroll
        for (int d = 0; d < NBAND; d++) {
            const int j = i + d - 4;
            if (j >= 0 && j < LSEQ) { acc[d] += brow[j]; m = fmaxf(m, acc[d]); }
        }
        float p[NBAND];
        float s = 0.f;
#pragma unroll
        for (int d = 0; d < NBAND; d++) {
            const int j = i + d - 4;
            p[d] = (j >= 0 && j < LSEQ) ? expf(acc[d] - m) : 0.f;
            s += p[d];
        }
        const float inv = 1.f / s;
#pragma unroll
        for (int d = 0; d < NBAND; d++) band[(size_t)r * NBAND + d] = p[d] * inv;
    }
}

// ---------------------------------------------------------------------------
// Expand band probs into dense [B, L, L] output.
// ---------------------------------------------------------------------------
__global__ __launch_bounds__(256) void expand_band(const float* __restrict__ band,
                                                   float* __restrict__ out) {
    const size_t idx4 = (size_t)blockIdx.x * 256 + threadIdx.x;
    const size_t flat = idx4 * 4;
    const int j0 = (int)(flat & (LSEQ - 1));
    const size_t row = flat >> 11;
    const int i = (int)(row & (LSEQ - 1));
    float v[4];
#pragma unroll
    for (int s = 0; s < 4; s++) {
        const int dj = (j0 + s) - i + 4;
        v[s] = (dj >= 0 && dj < NBAND) ? band[row * NBAND + dj] : 0.f;
    }
    float4 o = {v[0], v[1], v[2], v[3]};
    *reinterpret_cast<float4*>(&out[flat]) = o;
}

// ---------------------------------------------------------------------------
// Fallback fp32 path (ws too small): GEMM + old band.
// ---------------------------------------------------------------------------
__global__ __launch_bounds__(256) void gemm_nt_bias(const float* __restrict__ A,
                                                    const float* __restrict__ B,
                                                    const float* __restrict__ bias,
                                                    float* __restrict__ C) {
    __shared__ float As[8][132];
    __shared__ float Bs[8][132];
    const int tid = threadIdx.x;
    const int row0 = blockIdx.x * 128, col0 = blockIdx.y * 128;
    const int lr = tid >> 1, lc = (tid & 1) * 4;
    const int tx = tid & 15, ty = tid >> 4;
    float acc[2][2][4][4];
#pragma unroll
    for (int a = 0; a < 2; a++)
#pragma unroll
        for (int b = 0; b < 2; b++)
#pragma unroll
            for (int c = 0; c < 4; c++)
#pragma unroll
                for (int d = 0; d < 4; d++) acc[a][b][c][d] = 0.f;
    for (int k0 = 0; k0 < HDIM; k0 += 8) {
        float4 av = *reinterpret_cast<const float4*>(&A[(size_t)(row0 + lr) * HDIM + k0 + lc]);
        float4 bv = *reinterpret_cast<const float4*>(&B[(size_t)(col0 + lr) * HDIM + k0 + lc]);
        __syncthreads();
        As[lc + 0][lr] = av.x; As[lc + 1][lr] = av.y; As[lc + 2][lr] = av.z; As[lc + 3][lr] = av.w;
        Bs[lc + 0][lr] = bv.x; Bs[lc + 1][lr] = bv.y; Bs[lc + 2][lr] = bv.z; Bs[lc + 3][lr] = bv.w;
        __syncthreads();
#pragma unroll
        for (int kk = 0; kk < 8; kk++) {
            float4 a0 = *reinterpret_cast<const float4*>(&As[kk][ty * 4]);
            float4 a1 = *reinterpret_cast<const float4*>(&As[kk][64 + ty * 4]);
            float4 b0 = *reinterpret_cast<const float4*>(&Bs[kk][tx * 4]);
            float4 b1 = *reinterpret_cast<const float4*>(&Bs[kk][64 + tx * 4]);
            float am[2][4] = {{a0.x, a0.y, a0.z, a0.w}, {a1.x, a1.y, a1.z, a1.w}};
            float bw[2][4] = {{b0.x, b0.y, b0.z, b0.w}, {b1.x, b1.y, b1.z, b1.w}};
#pragma unroll
            for (int mi = 0; mi < 2; mi++)
#pragma unroll
                for (int ni = 0; ni < 2; ni++)
#pragma unroll
                    for (int mm = 0; mm < 4; mm++)
#pragma unroll
                        for (int nn = 0; nn < 4; nn++)
                            acc[mi][ni][mm][nn] += am[mi][mm] * bw[ni][nn];
        }
    }
#pragma unroll
    for (int mi = 0; mi < 2; mi++)
#pragma unroll
        for (int mm = 0; mm < 4; mm++) {
            const int r = row0 + mi * 64 + ty * 4 + mm;
#pragma unroll
            for (int ni = 0; ni < 2; ni++) {
                const int c = col0 + ni * 64 + tx * 4;
                float4 o;
                o.x = acc[mi][ni][mm][0] + bias[c + 0];
                o.y = acc[mi][ni][mm][1] + bias[c + 1];
                o.z = acc[mi][ni][mm][2] + bias[c + 2];
                o.w = acc[mi][ni][mm][3] + bias[c + 3];
                *reinterpret_cast<float4*>(&C[(size_t)r * HDIM + c]) = o;
            }
        }
}

__global__ __launch_bounds__(256) void band_softmax(const float* __restrict__ qs,
                                                    const float* __restrict__ ks,
                                                    float* __restrict__ band) {
    const int wave = threadIdx.x >> 6;
    const int lane = threadIdx.x & 63;
    const int r = blockIdx.x * 4 + wave;
    const int b = r >> 11;
    const int i = r & (LSEQ - 1);
    const float* qrow = qs + (size_t)r * HDIM;
    const float* kbase = ks + (size_t)b * LSEQ * HDIM;
    float acc[NBAND];
#pragma unroll
    for (int d = 0; d < NBAND; d++) acc[d] = 0.f;
    for (int h = lane; h < HDIM; h += 64) {
        const float qv = qrow[h];
#pragma unroll
        for (int d = 0; d < NBAND; d++) {
            const int j = i + d - 4;
            if (j >= 0 && j < LSEQ)
                acc[d] += qv * kbase[(size_t)j * HDIM + h];
        }
    }
#pragma unroll
    for (int d = 0; d < NBAND; d++) {
        float v = acc[d];
#pragma unroll
        for (int off = 32; off > 0; off >>= 1) v += __shfl_xor(v, off, 64);
        acc[d] = v;
    }
    if (lane == 0) {
        float m = -1e30f;
#pragma unroll
        for (int d = 0; d < NBAND; d++) {
            const int j = i + d - 4;
            if (j >= 0 && j < LSEQ) m = fmaxf(m, acc[d]);
        }
        float p[NBAND];
        float s = 0.f;
#pragma unroll
        for (int d = 0; d < NBAND; d++) {
            const int j = i + d - 4;
            p[d] = (j >= 0 && j < LSEQ) ? expf(acc[d] - m) : 0.f;
            s += p[d];
        }
        const float inv = 1.f / s;
#pragma unroll
        for (int d = 0; d < NBAND; d++) band[(size_t)r * NBAND + d] = p[d] * inv;
    }
}

extern "C" void kernel_launch(void* const* d_in, const int* in_sizes, int n_in,
                              void* d_out, int out_size, void* d_ws, size_t ws_size,
                              hipStream_t stream) {
    const float* q  = (const float*)d_in[0];
    const float* k  = (const float*)d_in[1];
    const float* Wq = (const float*)d_in[2];
    const float* bq = (const float*)d_in[3];
    const float* Wk = (const float*)d_in[4];
    const float* bk = (const float*)d_in[5];
    float* out = (float*)d_out;

    // ---- workspace layout (36.4 MB) ----
    const size_t bandB = (size_t)ROWS * NBAND * sizeof(float);            // 294,912
    char* p = (char*)d_ws;
    float* band = (float*)p;                 p += bandB;
    unsigned short* Xhi = (unsigned short*)p; p += (size_t)ROWS * HDIM * 2;   // 16 MB
    unsigned short* Xlo = (unsigned short*)p; p += (size_t)ROWS * HDIM * 2;   // 16 MB
    unsigned short* Mhi = (unsigned short*)p; p += (size_t)HDIM * HDIM * 2;   // 2 MB
    unsigned short* Mlo = (unsigned short*)p; p += (size_t)HDIM * HDIM * 2;   // 2 MB
    float* w        = (float*)p;             p += HDIM * sizeof(float);
    float* wpart    = (float*)p;             p += 16 * HDIM * sizeof(float);
    float* beta     = (float*)p;             p += ROWS * sizeof(float);
    float* zerobias = (float*)p;             p += HDIM * sizeof(float);
    const size_t need = (size_t)(p - (char*)d_ws);

    // WqT/WkT bf16 splits live in the (not-yet-written) Xhi region (8 MB < 32 MB)
    unsigned short* WqTh = Xhi;
    unsigned short* WqTl = Xhi + (size_t)HDIM * HDIM;
    unsigned short* WkTh = Xhi + 2 * (size_t)HDIM * HDIM;
    unsigned short* WkTl = Xhi + 3 * (size_t)HDIM * HDIM;

    // M scratch in d_out: t -> [0, 8.4M floats); Mparts -> [8.4M, 16.8M)
    float* t = out;
    float* Mparts = out + (size_t)ROWS * HDIM;

    if (ws_size >= need) {
        // 1-2: w = Wk^T bq (deterministic two-pass), zerobias = 0
        wpart_kernel<<<16, 256, 0, stream>>>(Wk, bq, wpart);
        wreduce_zero<<<8, 256, 0, stream>>>(wpart, w, zerobias);
        // 3: WqT/WkT split-bf16 (transposed)
        dim3 tg(16, 16, 2);
        transpose_convert<<<tg, 256, 0, stream>>>(Wq, Wk, WqTh, WqTl, WkTh, WkTl);
        // 4: M[e,f] = sum_h Wq[h,e] Wk[h,f], split-K=8 into Mparts
        dim3 mg(8, 8, 8);
        gemm_part<<<mg, 256, 0, stream>>>(WqTh, WqTl, WkTh, WkTl, Mparts);
        // 5: M = sum parts -> bf16 hi/lo
        reduceM_convert<<<HDIM * HDIM / 4 / 256, 256, 0, stream>>>(Mparts, Mhi, Mlo);
        // 6: k -> bf16 hi/lo + beta = K @ w   (overwrites WqT/WkT region - dead)
        convert_k_beta<<<ROWS, 256, 0, stream>>>(k, w, Xhi, Xlo, beta);
        // 7: t = K @ M^T
        dim3 gg(ROWS / 128, HDIM / 128);
        gemm_mfma_split<<<gg, 256, 0, stream>>>(Xhi, Xlo, Mhi, Mlo, zerobias, t);
        // 8: band softmax from q (raw) . t + beta
        band_softmax_v2<<<ROWS / 4, 256, 0, stream>>>(q, t, beta, band);
        // 9: expand
        expand_band<<<(size_t)ROWS * LSEQ / 4 / 256, 256, 0, stream>>>(band, out);
    } else {
        float* qs = out;
        float* ks = out + (size_t)ROWS * HDIM;
        dim3 gg(ROWS / 128, HDIM / 128);
        gemm_nt_bias<<<gg, 256, 0, stream>>>(q, Wq, bq, qs);
        gemm_nt_bias<<<gg, 256, 0, stream>>>(k, Wk, bk, ks);
        band_softmax<<<ROWS / 4, 256, 0, stream>>>(qs, ks, band);
        expand_band<<<(size_t)ROWS * LSEQ / 4 / 256, 256, 0, stream>>>(band, out);
    }
}

// Round 5
// 150.722 us; speedup vs baseline: 3.2195x; 1.0553x over previous
//
#include <hip/hip_runtime.h>
#include <math.h>

#define LSEQ 2048
#define HDIM 1024
#define BATCH 4
#define ROWS (BATCH * LSEQ)   // 8192
#define NBAND 9               // |i-j| <= 4

typedef __attribute__((ext_vector_type(8))) short bf16x8;
typedef __attribute__((ext_vector_type(4))) float f32x4;
typedef __attribute__((ext_vector_type(8))) unsigned short u16x8;

#define AS3 __attribute__((address_space(3)))
#define AS1 __attribute__((address_space(1)))

__device__ __forceinline__ void gload16(const void* gp, void* lp) {
    __builtin_amdgcn_global_load_lds((AS1 const unsigned*)gp, (AS3 unsigned*)lp, 16, 0, 0);
}

__device__ __forceinline__ unsigned short f2bf(float x) {
    unsigned u = __float_as_uint(x);
    u += 0x7FFFu + ((u >> 16) & 1u);
    return (unsigned short)(u >> 16);
}
__device__ __forceinline__ float bf2f(unsigned short h) {
    return __uint_as_float(((unsigned)h) << 16);
}

// ---------------------------------------------------------------------------
// w partial: wpart[blk][c] = sum_{h in blk range} Wk[h,c] * bq[h] (64 blocks)
// ---------------------------------------------------------------------------
__global__ __launch_bounds__(256) void wpart_kernel(const float* __restrict__ Wk,
                                                    const float* __restrict__ bq,
                                                    float* __restrict__ wpart) {
    const int b = blockIdx.x;          // 0..63, h range [b*16, b*16+16)
    const int c0 = threadIdx.x * 4;
    float4 acc = {0.f, 0.f, 0.f, 0.f};
#pragma unroll
    for (int hh = 0; hh < 16; hh++) {
        const int h = b * 16 + hh;
        const float s = bq[h];
        float4 v = *reinterpret_cast<const float4*>(&Wk[(size_t)h * HDIM + c0]);
        acc.x += v.x * s; acc.y += v.y * s; acc.z += v.z * s; acc.w += v.w * s;
    }
    *reinterpret_cast<float4*>(&wpart[(size_t)b * HDIM + c0]) = acc;
}

// blocks 0..3: w[c] = sum_b wpart[b][c];  blocks 4..7: zerobias = 0
__global__ __launch_bounds__(256) void wreduce_zero(const float* __restrict__ wpart,
                                                    float* __restrict__ w,
                                                    float* __restrict__ zerobias) {
    const int blk = blockIdx.x;
    const int t = threadIdx.x;
    if (blk < 4) {
        const int c = blk * 256 + t;
        float s = 0.f;
#pragma unroll
        for (int b = 0; b < 64; b++) s += wpart[(size_t)b * HDIM + c];
        w[c] = s;
    } else {
        zerobias[(blk - 4) * 256 + t] = 0.f;
    }
}

// ---------------------------------------------------------------------------
// Transposed split-convert: dst[n,h] = split(src[h,n]); z=0 -> Wq, z=1 -> Wk
// ---------------------------------------------------------------------------
__global__ __launch_bounds__(256) void transpose_convert(const float* __restrict__ Wq,
                                                         const float* __restrict__ Wk,
                                                         unsigned short* __restrict__ qhi,
                                                         unsigned short* __restrict__ qlo,
                                                         unsigned short* __restrict__ khi,
                                                         unsigned short* __restrict__ klo) {
    __shared__ float tile[64][65];
    const int z = blockIdx.z;
    const float* src = z ? Wk : Wq;
    unsigned short* dh = z ? khi : qhi;
    unsigned short* dl = z ? klo : qlo;
    const int n0 = blockIdx.x * 64;
    const int h0 = blockIdx.y * 64;
    const int tid = threadIdx.x;

#pragma unroll
    for (int p = 0; p < 4; p++) {
        const int h = p * 16 + (tid >> 4);
        const int n = (tid & 15) * 4;
        float4 v = *reinterpret_cast<const float4*>(&src[(size_t)(h0 + h) * HDIM + n0 + n]);
        tile[h][n + 0] = v.x; tile[h][n + 1] = v.y; tile[h][n + 2] = v.z; tile[h][n + 3] = v.w;
    }
    __syncthreads();
#pragma unroll
    for (int p = 0; p < 2; p++) {
        const int n = p * 32 + (tid >> 3);
        const int h = (tid & 7) * 8;
        u16x8 hv, lv;
#pragma unroll
        for (int j = 0; j < 8; j++) {
            float x = tile[h + j][n];
            unsigned short hb = f2bf(x);
            hv[j] = hb;
            lv[j] = f2bf(x - bf2f(hb));
        }
        *reinterpret_cast<u16x8*>(&dh[(size_t)(n0 + n) * HDIM + h0 + h]) = hv;
        *reinterpret_cast<u16x8*>(&dl[(size_t)(n0 + n) * HDIM + h0 + h]) = lv;
    }
}

// ---------------------------------------------------------------------------
// Fused: split-convert k rows to bf16 hi/lo AND beta[r] = k_r . w
// ---------------------------------------------------------------------------
__global__ __launch_bounds__(256) void convert_k_beta(const float* __restrict__ k,
                                                      const float* __restrict__ w,
                                                      unsigned short* __restrict__ Xhi,
                                                      unsigned short* __restrict__ Xlo,
                                                      float* __restrict__ beta) {
    __shared__ float red[4];
    const int r = blockIdx.x;
    const int t = threadIdx.x;
    float4 v = *reinterpret_cast<const float4*>(&k[(size_t)r * HDIM + t * 4]);
    float4 wv = *reinterpret_cast<const float4*>(&w[t * 4]);
    ushort4 h, l;
    h.x = f2bf(v.x); l.x = f2bf(v.x - bf2f(h.x));
    h.y = f2bf(v.y); l.y = f2bf(v.y - bf2f(h.y));
    h.z = f2bf(v.z); l.z = f2bf(v.z - bf2f(h.z));
    h.w = f2bf(v.w); l.w = f2bf(v.w - bf2f(h.w));
    reinterpret_cast<ushort4*>(Xhi)[(size_t)r * 256 + t] = h;
    reinterpret_cast<ushort4*>(Xlo)[(size_t)r * 256 + t] = l;
    float d = v.x * wv.x + v.y * wv.y + v.z * wv.z + v.w * wv.w;
#pragma unroll
    for (int off = 32; off > 0; off >>= 1) d += __shfl_xor(d, off, 64);
    if ((t & 63) == 0) red[t >> 6] = d;
    __syncthreads();
    if (t == 0) beta[r] = red[0] + red[1] + red[2] + red[3];
}

// ---------------------------------------------------------------------------
// Split-bf16 MFMA GEMM (NT) + bias (verified round 3).
// ---------------------------------------------------------------------------
__global__ __launch_bounds__(256, 2) void gemm_mfma_split(
        const unsigned short* __restrict__ Ahi, const unsigned short* __restrict__ Alo,
        const unsigned short* __restrict__ Bhi, const unsigned short* __restrict__ Blo,
        const float* __restrict__ bias, float* __restrict__ C) {
    __shared__ unsigned short sh[4 * 4096];
    const int AHI = 0, ALO = 4096, BHI = 8192, BLO = 12288;
    const int tid = threadIdx.x;
    const int w = tid >> 6, l = tid & 63;
    const int wr = w >> 1, wc = w & 1;
    const int row0 = blockIdx.x * 128, col0 = blockIdx.y * 128;
    const int srow0 = (l >> 2), scbp = l & 3;

    f32x4 acc[4][4];
#pragma unroll
    for (int m = 0; m < 4; m++)
#pragma unroll
        for (int n = 0; n < 4; n++) acc[m][n] = (f32x4){0.f, 0.f, 0.f, 0.f};

    const int fr_a[4] = {wr * 64 + (l & 15), wr * 64 + 16 + (l & 15),
                         wr * 64 + 32 + (l & 15), wr * 64 + 48 + (l & 15)};
    const int fr_b[4] = {wc * 64 + (l & 15), wc * 64 + 16 + (l & 15),
                         wc * 64 + 32 + (l & 15), wc * 64 + 48 + (l & 15)};
    const int cb = l >> 4;

    for (int k0 = 0; k0 < HDIM; k0 += 32) {
#pragma unroll
        for (int i = 0; i < 2; i++) {
            const int seg = i * 4 + w;
            const int row = seg * 16 + srow0;
            const int cbs = scbp ^ ((row >> 1) & 3);
            gload16(Ahi + (size_t)(row0 + row) * HDIM + k0 + cbs * 8, &sh[AHI + seg * 512]);
            gload16(Alo + (size_t)(row0 + row) * HDIM + k0 + cbs * 8, &sh[ALO + seg * 512]);
            gload16(Bhi + (size_t)(col0 + row) * HDIM + k0 + cbs * 8, &sh[BHI + seg * 512]);
            gload16(Blo + (size_t)(col0 + row) * HDIM + k0 + cbs * 8, &sh[BLO + seg * 512]);
        }
        __syncthreads();

        bf16x8 ah[4], al[4], bh[4], bl[4];
#pragma unroll
        for (int m = 0; m < 4; m++) {
            const int r = fr_a[m];
            const int cbs = cb ^ ((r >> 1) & 3);
            ah[m] = *reinterpret_cast<const bf16x8*>(&sh[AHI + r * 32 + cbs * 8]);
            al[m] = *reinterpret_cast<const bf16x8*>(&sh[ALO + r * 32 + cbs * 8]);
        }
#pragma unroll
        for (int n = 0; n < 4; n++) {
            const int r = fr_b[n];
            const int cbs = cb ^ ((r >> 1) & 3);
            bh[n] = *reinterpret_cast<const bf16x8*>(&sh[BHI + r * 32 + cbs * 8]);
            bl[n] = *reinterpret_cast<const bf16x8*>(&sh[BLO + r * 32 + cbs * 8]);
        }
#pragma unroll
        for (int m = 0; m < 4; m++)
#pragma unroll
            for (int n = 0; n < 4; n++) {
                acc[m][n] = __builtin_amdgcn_mfma_f32_16x16x32_bf16(ah[m], bh[n], acc[m][n], 0, 0, 0);
                acc[m][n] = __builtin_amdgcn_mfma_f32_16x16x32_bf16(ah[m], bl[n], acc[m][n], 0, 0, 0);
                acc[m][n] = __builtin_amdgcn_mfma_f32_16x16x32_bf16(al[m], bh[n], acc[m][n], 0, 0, 0);
            }
        __syncthreads();
    }

    const int lcol = l & 15, lrow = (l >> 4) * 4;
#pragma unroll
    for (int n = 0; n < 4; n++) {
        const int colg = col0 + wc * 64 + n * 16 + lcol;
        const float bv = bias[colg];
#pragma unroll
        for (int m = 0; m < 4; m++) {
            const int rowg = row0 + wr * 64 + m * 16 + lrow;
#pragma unroll
            for (int v = 0; v < 4; v++)
                C[(size_t)(rowg + v) * HDIM + colg] = acc[m][n][v] + bv;
        }
    }
}

// ---------------------------------------------------------------------------
// Split-K GEMM for M = WqT @ WkT^T: grid (8,8,8).
// ---------------------------------------------------------------------------
__global__ __launch_bounds__(256, 2) void gemm_part(
        const unsigned short* __restrict__ Ahi, const unsigned short* __restrict__ Alo,
        const unsigned short* __restrict__ Bhi, const unsigned short* __restrict__ Blo,
        float* __restrict__ Cparts) {
    __shared__ unsigned short sh[4 * 4096];
    const int AHI = 0, ALO = 4096, BHI = 8192, BLO = 12288;
    const int tid = threadIdx.x;
    const int w = tid >> 6, l = tid & 63;
    const int wr = w >> 1, wc = w & 1;
    const int row0 = blockIdx.x * 128, col0 = blockIdx.y * 128;
    const int kbeg = blockIdx.z * 128;
    float* C = Cparts + (size_t)blockIdx.z * HDIM * HDIM;
    const int srow0 = (l >> 2), scbp = l & 3;

    f32x4 acc[4][4];
#pragma unroll
    for (int m = 0; m < 4; m++)
#pragma unroll
        for (int n = 0; n < 4; n++) acc[m][n] = (f32x4){0.f, 0.f, 0.f, 0.f};

    const int fr_a[4] = {wr * 64 + (l & 15), wr * 64 + 16 + (l & 15),
                         wr * 64 + 32 + (l & 15), wr * 64 + 48 + (l & 15)};
    const int fr_b[4] = {wc * 64 + (l & 15), wc * 64 + 16 + (l & 15),
                         wc * 64 + 32 + (l & 15), wc * 64 + 48 + (l & 15)};
    const int cb = l >> 4;

    for (int k0 = kbeg; k0 < kbeg + 128; k0 += 32) {
#pragma unroll
        for (int i = 0; i < 2; i++) {
            const int seg = i * 4 + w;
            const int row = seg * 16 + srow0;
            const int cbs = scbp ^ ((row >> 1) & 3);
            gload16(Ahi + (size_t)(row0 + row) * HDIM + k0 + cbs * 8, &sh[AHI + seg * 512]);
            gload16(Alo + (size_t)(row0 + row) * HDIM + k0 + cbs * 8, &sh[ALO + seg * 512]);
            gload16(Bhi + (size_t)(col0 + row) * HDIM + k0 + cbs * 8, &sh[BHI + seg * 512]);
            gload16(Blo + (size_t)(col0 + row) * HDIM + k0 + cbs * 8, &sh[BLO + seg * 512]);
        }
        __syncthreads();

        bf16x8 ah[4], al[4], bh[4], bl[4];
#pragma unroll
        for (int m = 0; m < 4; m++) {
            const int r = fr_a[m];
            const int cbs = cb ^ ((r >> 1) & 3);
            ah[m] = *reinterpret_cast<const bf16x8*>(&sh[AHI + r * 32 + cbs * 8]);
            al[m] = *reinterpret_cast<const bf16x8*>(&sh[ALO + r * 32 + cbs * 8]);
        }
#pragma unroll
        for (int n = 0; n < 4; n++) {
            const int r = fr_b[n];
            const int cbs = cb ^ ((r >> 1) & 3);
            bh[n] = *reinterpret_cast<const bf16x8*>(&sh[BHI + r * 32 + cbs * 8]);
            bl[n] = *reinterpret_cast<const bf16x8*>(&sh[BLO + r * 32 + cbs * 8]);
        }
#pragma unroll
        for (int m = 0; m < 4; m++)
#pragma unroll
            for (int n = 0; n < 4; n++) {
                acc[m][n] = __builtin_amdgcn_mfma_f32_16x16x32_bf16(ah[m], bh[n], acc[m][n], 0, 0, 0);
                acc[m][n] = __builtin_amdgcn_mfma_f32_16x16x32_bf16(ah[m], bl[n], acc[m][n], 0, 0, 0);
                acc[m][n] = __builtin_amdgcn_mfma_f32_16x16x32_bf16(al[m], bh[n], acc[m][n], 0, 0, 0);
            }
        __syncthreads();
    }

    const int lcol = l & 15, lrow = (l >> 4) * 4;
#pragma unroll
    for (int n = 0; n < 4; n++) {
        const int colg = col0 + wc * 64 + n * 16 + lcol;
#pragma unroll
        for (int m = 0; m < 4; m++) {
            const int rowg = row0 + wr * 64 + m * 16 + lrow;
#pragma unroll
            for (int v = 0; v < 4; v++)
                C[(size_t)(rowg + v) * HDIM + colg] = acc[m][n][v];
        }
    }
}

// ---------------------------------------------------------------------------
// Reduce 8 M-parts and split-convert to bf16 hi/lo.
// ---------------------------------------------------------------------------
__global__ __launch_bounds__(256) void reduceM_convert(const float* __restrict__ Mparts,
                                                       unsigned short* __restrict__ Mhi,
                                                       unsigned short* __restrict__ Mlo) {
    const int idx4 = blockIdx.x * 256 + threadIdx.x;
    float4 s = {0.f, 0.f, 0.f, 0.f};
#pragma unroll
    for (int z = 0; z < 8; z++) {
        float4 v = reinterpret_cast<const float4*>(Mparts + (size_t)z * HDIM * HDIM)[idx4];
        s.x += v.x; s.y += v.y; s.z += v.z; s.w += v.w;
    }
    ushort4 h, l;
    h.x = f2bf(s.x); l.x = f2bf(s.x - bf2f(h.x));
    h.y = f2bf(s.y); l.y = f2bf(s.y - bf2f(h.y));
    h.z = f2bf(s.z); l.z = f2bf(s.z - bf2f(h.z));
    h.w = f2bf(s.w); l.w = f2bf(s.w - bf2f(h.w));
    reinterpret_cast<ushort4*>(Mhi)[idx4] = h;
    reinterpret_cast<ushort4*>(Mlo)[idx4] = l;
}

// ---------------------------------------------------------------------------
// Band logits + softmax v3: float4 loads, 2 rows per wave (share t-rows).
// logit_d(i) = q_i . t_j + beta_j, j = i + d - 4.
// ---------------------------------------------------------------------------
__global__ __launch_bounds__(256) void band_softmax_v3(const float* __restrict__ q,
                                                       const float* __restrict__ t,
                                                       const float* __restrict__ beta,
                                                       float* __restrict__ band) {
    const int wave = threadIdx.x >> 6;
    const int lane = threadIdx.x & 63;
    const int pair = blockIdx.x * 4 + wave;   // 0..4095
    const int r0 = pair * 2;                  // even row; r0,r0+1 same batch
    const int b = r0 >> 11;
    const int i0 = r0 & (LSEQ - 1);

    const float4* q0 = reinterpret_cast<const float4*>(q + (size_t)r0 * HDIM);
    const float4* q1 = reinterpret_cast<const float4*>(q + (size_t)(r0 + 1) * HDIM);
    const float* tbase = t + (size_t)b * LSEQ * HDIM;

    float acc0[NBAND], acc1[NBAND];
#pragma unroll
    for (int d = 0; d < NBAND; d++) { acc0[d] = 0.f; acc1[d] = 0.f; }

#pragma unroll
    for (int it = 0; it < 4; it++) {
        const int h4 = it * 64 + lane;        // float4 index within row
        const float4 qa = q0[h4];
        const float4 qb = q1[h4];
#pragma unroll
        for (int jj = 0; jj < 10; jj++) {     // t rows i0-4 .. i0+5
            const int j = i0 + jj - 4;
            if (j >= 0 && j < LSEQ) {         // wave-uniform
                const float4 tv = reinterpret_cast<const float4*>(tbase + (size_t)j * HDIM)[h4];
                if (jj < 9)
                    acc0[jj] += qa.x * tv.x + qa.y * tv.y + qa.z * tv.z + qa.w * tv.w;
                if (jj >= 1)
                    acc1[jj - 1] += qb.x * tv.x + qb.y * tv.y + qb.z * tv.z + qb.w * tv.w;
            }
        }
    }

#pragma unroll
    for (int d = 0; d < NBAND; d++) {
        float v0 = acc0[d], v1 = acc1[d];
#pragma unroll
        for (int off = 32; off > 0; off >>= 1) {
            v0 += __shfl_xor(v0, off, 64);
            v1 += __shfl_xor(v1, off, 64);
        }
        acc0[d] = v0; acc1[d] = v1;
    }

    if (lane == 0) {
        const float* brow = beta + (size_t)b * LSEQ;
        // row r0 (i = i0)
        {
            float m = -1e30f;
            float lg[NBAND];
#pragma unroll
            for (int d = 0; d < NBAND; d++) {
                const int j = i0 + d - 4;
                lg[d] = (j >= 0 && j < LSEQ) ? acc0[d] + brow[j] : -1e30f;
                m = fmaxf(m, lg[d]);
            }
            float p[NBAND], s = 0.f;
#pragma unroll
            for (int d = 0; d < NBAND; d++) {
                const int j = i0 + d - 4;
                p[d] = (j >= 0 && j < LSEQ) ? expf(lg[d] - m) : 0.f;
                s += p[d];
            }
            const float inv = 1.f / s;
#pragma unroll
            for (int d = 0; d < NBAND; d++) band[(size_t)r0 * NBAND + d] = p[d] * inv;
        }
        // row r0+1 (i = i0+1)
        {
            const int i1 = i0 + 1;
            float m = -1e30f;
            float lg[NBAND];
#pragma unroll
            for (int d = 0; d < NBAND; d++) {
                const int j = i1 + d - 4;
                lg[d] = (j >= 0 && j < LSEQ) ? acc1[d] + brow[j] : -1e30f;
                m = fmaxf(m, lg[d]);
            }
            float p[NBAND], s = 0.f;
#pragma unroll
            for (int d = 0; d < NBAND; d++) {
                const int j = i1 + d - 4;
                p[d] = (j >= 0 && j < LSEQ) ? expf(lg[d] - m) : 0.f;
                s += p[d];
            }
            const float inv = 1.f / s;
#pragma unroll
            for (int d = 0; d < NBAND; d++) band[(size_t)(r0 + 1) * NBAND + d] = p[d] * inv;
        }
    }
}

// ---------------------------------------------------------------------------
// Expand band probs into dense [B, L, L] output.
// ---------------------------------------------------------------------------
__global__ __launch_bounds__(256) void expand_band(const float* __restrict__ band,
                                                   float* __restrict__ out) {
    const size_t idx4 = (size_t)blockIdx.x * 256 + threadIdx.x;
    const size_t flat = idx4 * 4;
    const int j0 = (int)(flat & (LSEQ - 1));
    const size_t row = flat >> 11;
    const int i = (int)(row & (LSEQ - 1));
    float v[4];
#pragma unroll
    for (int s = 0; s < 4; s++) {
        const int dj = (j0 + s) - i + 4;
        v[s] = (dj >= 0 && dj < NBAND) ? band[row * NBAND + dj] : 0.f;
    }
    float4 o = {v[0], v[1], v[2], v[3]};
    *reinterpret_cast<float4*>(&out[flat]) = o;
}

// ---------------------------------------------------------------------------
// Fallback fp32 path (ws too small).
// ---------------------------------------------------------------------------
__global__ __launch_bounds__(256) void gemm_nt_bias(const float* __restrict__ A,
                                                    const float* __restrict__ B,
                                                    const float* __restrict__ bias,
                                                    float* __restrict__ C) {
    __shared__ float As[8][132];
    __shared__ float Bs[8][132];
    const int tid = threadIdx.x;
    const int row0 = blockIdx.x * 128, col0 = blockIdx.y * 128;
    const int lr = tid >> 1, lc = (tid & 1) * 4;
    const int tx = tid & 15, ty = tid >> 4;
    float acc[2][2][4][4];
#pragma unroll
    for (int a = 0; a < 2; a++)
#pragma unroll
        for (int b = 0; b < 2; b++)
#pragma unroll
            for (int c = 0; c < 4; c++)
#pragma unroll
                for (int d = 0; d < 4; d++) acc[a][b][c][d] = 0.f;
    for (int k0 = 0; k0 < HDIM; k0 += 8) {
        float4 av = *reinterpret_cast<const float4*>(&A[(size_t)(row0 + lr) * HDIM + k0 + lc]);
        float4 bv = *reinterpret_cast<const float4*>(&B[(size_t)(col0 + lr) * HDIM + k0 + lc]);
        __syncthreads();
        As[lc + 0][lr] = av.x; As[lc + 1][lr] = av.y; As[lc + 2][lr] = av.z; As[lc + 3][lr] = av.w;
        Bs[lc + 0][lr] = bv.x; Bs[lc + 1][lr] = bv.y; Bs[lc + 2][lr] = bv.z; Bs[lc + 3][lr] = bv.w;
        __syncthreads();
#pragma unroll
        for (int kk = 0; kk < 8; kk++) {
            float4 a0 = *reinterpret_cast<const float4*>(&As[kk][ty * 4]);
            float4 a1 = *reinterpret_cast<const float4*>(&As[kk][64 + ty * 4]);
            float4 b0 = *reinterpret_cast<const float4*>(&Bs[kk][tx * 4]);
            float4 b1 = *reinterpret_cast<const float4*>(&Bs[kk][64 + tx * 4]);
            float am[2][4] = {{a0.x, a0.y, a0.z, a0.w}, {a1.x, a1.y, a1.z, a1.w}};
            float bw[2][4] = {{b0.x, b0.y, b0.z, b0.w}, {b1.x, b1.y, b1.z, b1.w}};
#pragma unroll
            for (int mi = 0; mi < 2; mi++)
#pragma unroll
                for (int ni = 0; ni < 2; ni++)
#pragma unroll
                    for (int mm = 0; mm < 4; mm++)
#pragma unroll
                        for (int nn = 0; nn < 4; nn++)
                            acc[mi][ni][mm][nn] += am[mi][mm] * bw[ni][nn];
        }
    }
#pragma unroll
    for (int mi = 0; mi < 2; mi++)
#pragma unroll
        for (int mm = 0; mm < 4; mm++) {
            const int r = row0 + mi * 64 + ty * 4 + mm;
#pragma unroll
            for (int ni = 0; ni < 2; ni++) {
                const int c = col0 + ni * 64 + tx * 4;
                float4 o;
                o.x = acc[mi][ni][mm][0] + bias[c + 0];
                o.y = acc[mi][ni][mm][1] + bias[c + 1];
                o.z = acc[mi][ni][mm][2] + bias[c + 2];
                o.w = acc[mi][ni][mm][3] + bias[c + 3];
                *reinterpret_cast<float4*>(&C[(size_t)r * HDIM + c]) = o;
            }
        }
}

__global__ __launch_bounds__(256) void band_softmax(const float* __restrict__ qs,
                                                    const float* __restrict__ ks,
                                                    float* __restrict__ band) {
    const int wave = threadIdx.x >> 6;
    const int lane = threadIdx.x & 63;
    const int r = blockIdx.x * 4 + wave;
    const int b = r >> 11;
    const int i = r & (LSEQ - 1);
    const float* qrow = qs + (size_t)r * HDIM;
    const float* kbase = ks + (size_t)b * LSEQ * HDIM;
    float acc[NBAND];
#pragma unroll
    for (int d = 0; d < NBAND; d++) acc[d] = 0.f;
    for (int h = lane; h < HDIM; h += 64) {
        const float qv = qrow[h];
#pragma unroll
        for (int d = 0; d < NBAND; d++) {
            const int j = i + d - 4;
            if (j >= 0 && j < LSEQ)
                acc[d] += qv * kbase[(size_t)j * HDIM + h];
        }
    }
#pragma unroll
    for (int d = 0; d < NBAND; d++) {
        float v = acc[d];
#pragma unroll
        for (int off = 32; off > 0; off >>= 1) v += __shfl_xor(v, off, 64);
        acc[d] = v;
    }
    if (lane == 0) {
        float m = -1e30f;
#pragma unroll
        for (int d = 0; d < NBAND; d++) {
            const int j = i + d - 4;
            if (j >= 0 && j < LSEQ) m = fmaxf(m, acc[d]);
        }
        float p[NBAND];
        float s = 0.f;
#pragma unroll
        for (int d = 0; d < NBAND; d++) {
            const int j = i + d - 4;
            p[d] = (j >= 0 && j < LSEQ) ? expf(acc[d] - m) : 0.f;
            s += p[d];
        }
        const float inv = 1.f / s;
#pragma unroll
        for (int d = 0; d < NBAND; d++) band[(size_t)r * NBAND + d] = p[d] * inv;
    }
}

extern "C" void kernel_launch(void* const* d_in, const int* in_sizes, int n_in,
                              void* d_out, int out_size, void* d_ws, size_t ws_size,
                              hipStream_t stream) {
    const float* q  = (const float*)d_in[0];
    const float* k  = (const float*)d_in[1];
    const float* Wq = (const float*)d_in[2];
    const float* bq = (const float*)d_in[3];
    const float* Wk = (const float*)d_in[4];
    const float* bk = (const float*)d_in[5];
    float* out = (float*)d_out;

    // ---- workspace layout (~36.7 MB) ----
    const size_t bandB = (size_t)ROWS * NBAND * sizeof(float);
    char* p = (char*)d_ws;
    float* band = (float*)p;                 p += bandB;
    unsigned short* Xhi = (unsigned short*)p; p += (size_t)ROWS * HDIM * 2;   // 16 MB
    unsigned short* Xlo = (unsigned short*)p; p += (size_t)ROWS * HDIM * 2;   // 16 MB
    unsigned short* Mhi = (unsigned short*)p; p += (size_t)HDIM * HDIM * 2;   // 2 MB
    unsigned short* Mlo = (unsigned short*)p; p += (size_t)HDIM * HDIM * 2;   // 2 MB
    float* w        = (float*)p;             p += HDIM * sizeof(float);
    float* wpart    = (float*)p;             p += 64 * HDIM * sizeof(float);
    float* beta     = (float*)p;             p += ROWS * sizeof(float);
    float* zerobias = (float*)p;             p += HDIM * sizeof(float);
    const size_t need = (size_t)(p - (char*)d_ws);

    // WqT/WkT bf16 splits live in the (not-yet-written) Xhi region
    unsigned short* WqTh = Xhi;
    unsigned short* WqTl = Xhi + (size_t)HDIM * HDIM;
    unsigned short* WkTh = Xhi + 2 * (size_t)HDIM * HDIM;
    unsigned short* WkTl = Xhi + 3 * (size_t)HDIM * HDIM;

    // M scratch in d_out: t -> [0, 8.4M floats); Mparts -> [8.4M, 16.8M)
    float* t = out;
    float* Mparts = out + (size_t)ROWS * HDIM;

    if (ws_size >= need) {
        wpart_kernel<<<64, 256, 0, stream>>>(Wk, bq, wpart);
        wreduce_zero<<<8, 256, 0, stream>>>(wpart, w, zerobias);
        dim3 tg(16, 16, 2);
        transpose_convert<<<tg, 256, 0, stream>>>(Wq, Wk, WqTh, WqTl, WkTh, WkTl);
        dim3 mg(8, 8, 8);
        gemm_part<<<mg, 256, 0, stream>>>(WqTh, WqTl, WkTh, WkTl, Mparts);
        reduceM_convert<<<HDIM * HDIM / 4 / 256, 256, 0, stream>>>(Mparts, Mhi, Mlo);
        convert_k_beta<<<ROWS, 256, 0, stream>>>(k, w, Xhi, Xlo, beta);
        dim3 gg(ROWS / 128, HDIM / 128);
        gemm_mfma_split<<<gg, 256, 0, stream>>>(Xhi, Xlo, Mhi, Mlo, zerobias, t);
        band_softmax_v3<<<ROWS / 8, 256, 0, stream>>>(q, t, beta, band);
        expand_band<<<(size_t)ROWS * LSEQ / 4 / 256, 256, 0, stream>>>(band, out);
    } else {
        float* qs = out;
        float* ks = out + (size_t)ROWS * HDIM;
        dim3 gg(ROWS / 128, HDIM / 128);
        gemm_nt_bias<<<gg, 256, 0, stream>>>(q, Wq, bq, qs);
        gemm_nt_bias<<<gg, 256, 0, stream>>>(k, Wk, bk, ks);
        band_softmax<<<ROWS / 4, 256, 0, stream>>>(qs, ks, band);
        expand_band<<<(size_t)ROWS * LSEQ / 4 / 256, 256, 0, stream>>>(band, out);
    }
}